// Round 1
// baseline (258.688 us; speedup 1.0000x reference)
//
#include <hip/hip_runtime.h>

// Depthwise 2x2 Haar high-pass, stride 1, VALID.
// in:  (B=4, C=128, H=512, W=512) fp32
// out: (B,   C,     H-1,   W-1)   fp32
// out[y,x] = 0.5*(in[y,x] - in[y,x+1] - in[y+1,x] + in[y+1,x+1])

#define Bn 4
#define Cn 128
#define Hn 512
#define Wn 512
#define OH (Hn - 1)
#define OW (Wn - 1)
#define ROWS 64      // output rows per block
#define TPB 128      // threads per block; 128*4 = 512 cols covered

typedef float f4 __attribute__((ext_vector_type(4)));
typedef float f4u __attribute__((ext_vector_type(4), aligned(4)));  // 4B-aligned stores

__global__ __launch_bounds__(TPB)
void haar_kernel(const float* __restrict__ in, float* __restrict__ out) {
    const int ch      = blockIdx.y;            // 0 .. B*C-1
    const int rowTile = blockIdx.x;            // 0 .. 7
    const int x0      = threadIdx.x * 4;       // 0,4,...,508
    const int y0      = rowTile * ROWS;

    const float* __restrict__ inCh  = in  + (size_t)ch * Hn * Wn;
    float* __restrict__       outCh = out + (size_t)ch * OH * OW;

    // Top row of the tile (aligned float4: row stride 512 floats, x0 % 4 == 0)
    const float* rowT = inCh + (size_t)y0 * Wn + x0;
    f4 top = *reinterpret_cast<const f4*>(rowT);
    float t4 = (x0 + 4 < Wn) ? rowT[4] : 0.0f;

    const int ylim = (OH - y0 < ROWS) ? (OH - y0) : ROWS;

    for (int r = 0; r < ylim; ++r) {
        const int y = y0 + r;
        const float* rowB = inCh + (size_t)(y + 1) * Wn + x0;
        f4 bot = *reinterpret_cast<const f4*>(rowB);
        float b4 = (x0 + 4 < Wn) ? rowB[4] : 0.0f;

        f4 o;
        o.x = 0.5f * (top.x - top.y - bot.x + bot.y);
        o.y = 0.5f * (top.y - top.z - bot.y + bot.z);
        o.z = 0.5f * (top.z - top.w - bot.z + bot.w);
        o.w = 0.5f * (top.w - t4   - bot.w + b4);

        float* op = outCh + (size_t)y * OW + x0;
        if (x0 + 4 <= OW) {
            *reinterpret_cast<f4u*>(op) = o;   // 4B-aligned dwordx4 store
        } else {
            // x0 == 508: only cols 508,509,510 are valid outputs
            op[0] = o.x; op[1] = o.y; op[2] = o.z;
        }

        top = bot;
        t4  = b4;
    }
}

extern "C" void kernel_launch(void* const* d_in, const int* in_sizes, int n_in,
                              void* d_out, int out_size, void* d_ws, size_t ws_size,
                              hipStream_t stream) {
    const float* x = (const float*)d_in[0];
    float* out = (float*)d_out;

    dim3 grid((OH + ROWS - 1) / ROWS, Bn * Cn);  // (8, 512)
    dim3 block(TPB);
    haar_kernel<<<grid, block, 0, stream>>>(x, out);
}